// Round 4
// baseline (286.190 us; speedup 1.0000x reference)
//
#include <hip/hip_runtime.h>
#include <hip/hip_bf16.h>

#define B 2
#define S 8192
#define H 16
#define D 64
#define NB 32          // S / BS
#define BS 256
#define SAMP 256
#define BH (B*H)
#define BHS (B*H*S)
#define LOG32 3.4657359027997265f   // log(8192/256)

typedef float f32x4 __attribute__((ext_vector_type(4)));
typedef short bf16x8 __attribute__((ext_vector_type(8)));

__device__ __forceinline__ unsigned short f2bf(float x) {
    unsigned int u = __builtin_bit_cast(unsigned int, x);
    u += 0x7fffu + ((u >> 16) & 1u);       // round-to-nearest-even
    return (unsigned short)(u >> 16);
}
__device__ __forceinline__ unsigned int pack2(float a, float b) {
    return (unsigned int)f2bf(a) | ((unsigned int)f2bf(b) << 16);
}

// ---------------------------------------------------------------------------
// Kernel 1: LSH hash only.  hash = gray(bin) = bin ^ (bin>>1).
// Block = 256 thr = 16 s-values x 16 heads -> wave footprint is a contiguous
// 16 KB region (lane stride 256 B), vs 256 KB sparse in R3.  Hash writes go
// through an LDS tile and out as coalesced int4 (16 consecutive s per (b,h)).
// ---------------------------------------------------------------------------
__device__ __forceinline__ int hash_row(const float* __restrict__ rp,
                                        const float* __restrict__ spd) {
    float d[8];
#pragma unroll
    for (int p = 0; p < 8; ++p) d[p] = 0.f;
#pragma unroll
    for (int i = 0; i < 8; ++i) {
        float4 x0 = ((const float4*)(rp + i * 8))[0];
        float4 x1 = ((const float4*)(rp + i * 8))[1];
#pragma unroll
        for (int p = 0; p < 8; ++p) {
            d[p] += x0.x * spd[(8*i+0)*8+p] + x0.y * spd[(8*i+1)*8+p]
                  + x0.z * spd[(8*i+2)*8+p] + x0.w * spd[(8*i+3)*8+p]
                  + x1.x * spd[(8*i+4)*8+p] + x1.y * spd[(8*i+5)*8+p]
                  + x1.z * spd[(8*i+6)*8+p] + x1.w * spd[(8*i+7)*8+p];
        }
    }
    int bits = 0;
#pragma unroll
    for (int p = 0; p < 8; ++p) bits |= (d[p] > 0.f) ? (1 << p) : 0;
    return bits ^ (bits >> 1);
}

__global__ __launch_bounds__(256) void k_hash(const float* __restrict__ q,
                                              const float* __restrict__ k,
                                              const float* __restrict__ pd,
                                              int* __restrict__ hq,
                                              int* __restrict__ hk) {
    __shared__ float spd[D * 8];
    __shared__ int   ht[2][16][16];   // [q/k][h][s_local]
    const int t = threadIdx.x;
    for (int i = t; i < D * 8; i += 256) spd[i] = pd[i];
    __syncthreads();

    const int b  = blockIdx.x >> 9;        // 512 s-chunks per batch
    const int s0 = (blockIdx.x & 511) * 16;
    const int sl = t >> 4;                 // s_local 0..15
    const int h  = t & 15;
    const int base = ((b * S + s0 + sl) * H + h) * D;

    ht[0][h][sl] = hash_row(q + base, spd);
    ht[1][h][sl] = hash_row(k + base, spd);
    __syncthreads();

    if (t < 128) {       // 2 arrays x 16 h x 4 int4 = 128 coalesced stores
        const int inp = t >> 6, r = t & 63, h2 = r >> 2, p2 = r & 3;
        int4 val = *(const int4*)&ht[inp][h2][p2 * 4];
        int* dst = inp ? hk : hq;
        *(int4*)&dst[(b * H + h2) * S + s0 + p2 * 4] = val;
    }
}

// ---------------------------------------------------------------------------
// Kernel 2: stable counting sort (argsort) of hashes per (b,h).  (unchanged)
// ---------------------------------------------------------------------------
#define SORT_NT 64
#define SORT_CH (S / SORT_NT)   // 128

__global__ __launch_bounds__(SORT_NT) void k_sort(const int* __restrict__ hq,
                                                  const int* __restrict__ hk,
                                                  int* __restrict__ qs,
                                                  int* __restrict__ ks) {
    __shared__ int hist[SORT_NT * 256];
    __shared__ int base[257];
    const int t  = threadIdx.x;
    const int bh = blockIdx.x & (BH - 1);
    const bool isQ = blockIdx.x < BH;
    const int* hp = (isQ ? hq : hk) + bh * S;
    int*       sp = (isQ ? qs : ks) + bh * S;

    for (int i = 0; i < 256; ++i) hist[t * 256 + i] = 0;
    __syncthreads();
    for (int i = 0; i < SORT_CH; ++i) hist[t * 256 + hp[t * SORT_CH + i]]++;
    __syncthreads();

    for (int bi = 0; bi < 4; ++bi) {
        const int bin = t * 4 + bi;
        int sum = 0;
        for (int tt = 0; tt < SORT_NT; ++tt) sum += hist[tt * 256 + bin];
        base[bin + 1] = sum;
    }
    __syncthreads();
    if (t == 0) {
        base[0] = 0;
        for (int i = 1; i <= 256; ++i) base[i] += base[i - 1];
    }
    __syncthreads();

    for (int bi = 0; bi < 4; ++bi) {
        const int bin = t * 4 + bi;
        int run = base[bin];
        for (int tt = 0; tt < SORT_NT; ++tt) {
            int c = hist[tt * 256 + bin];
            hist[tt * 256 + bin] = run;
            run += c;
        }
    }
    __syncthreads();

    for (int i = 0; i < SORT_CH; ++i) {
        const int s0  = t * SORT_CH + i;
        const int bin = hp[s0];
        sp[hist[t * 256 + bin]++] = s0;
    }
}

// ---------------------------------------------------------------------------
// Kernel 3: FUSED attention, f32 sources with inline bf16 conversion.
// One online softmax over 512 keys (pass0 = LSH block keys, pass1 = sampled
// keys with +LOG32 bias).  Swapped QK^T: c = mfma(A=K, B=Q) -> lane(lg,lr)
// holds P[query=lr][key=kg*16+lg*4+r] (keys in-lane => 2-shfl row reduce,
// packed b64 P writes).  PV: A=P, B=V^T.  512 thr = 8 waves x 32 queries.
// ---------------------------------------------------------------------------
#define VP 264    // vT pitch (256 + 8 pad)
#define PP 40     // per-wave P pitch (32 + 8 pad)

__global__ __launch_bounds__(512, 4) void k_attn(const float* __restrict__ q,
                                                 const float* __restrict__ k,
                                                 const float* __restrict__ v,
                                                 const int* __restrict__ qs,
                                                 const int* __restrict__ ks,
                                                 const int* __restrict__ sidx,
                                                 float* __restrict__ out) {
    __shared__ __align__(16) unsigned short vT[64 * VP];
    __shared__ __align__(16) unsigned short pL[8 * 32 * PP];

    const int t    = threadIdx.x;
    const int w    = t >> 6;
    const int lane = t & 63;
    const int lg   = lane >> 4;      // 0..3
    const int lr   = lane & 15;      // 0..15
    const int blk  = blockIdx.x & (NB - 1);
    const int bh   = blockIdx.x >> 5;
    const int h    = bh & (H - 1), b = bh >> 4;
    const int sbase = bh * S + blk * BS;
    unsigned short* pw = pL + w * 32 * PP;

    // ---- Q B-fragments (scale 1/8 folded into cvt) + query rows ----
    int qrow[2]; bf16x8 bq[2][2];
#pragma unroll
    for (int qg = 0; qg < 2; ++qg) {
        qrow[qg] = qs[sbase + w * 32 + qg * 16 + lr];
        const float* qp = q + (((b * S + qrow[qg]) * H + h) << 6);
#pragma unroll
        for (int kf = 0; kf < 2; ++kf) {
            float4 x0 = ((const float4*)(qp + kf * 32 + lg * 8))[0];
            float4 x1 = ((const float4*)(qp + kf * 32 + lg * 8))[1];
            union { bf16x8 v8; unsigned int u[4]; } fa;
            fa.u[0] = pack2(x0.x * 0.125f, x0.y * 0.125f);
            fa.u[1] = pack2(x0.z * 0.125f, x0.w * 0.125f);
            fa.u[2] = pack2(x1.x * 0.125f, x1.y * 0.125f);
            fa.u[3] = pack2(x1.z * 0.125f, x1.w * 0.125f);
            bq[qg][kf] = fa.v8;
        }
    }

    float m_run[2] = {-1e30f, -1e30f}, l_run[2] = {0.f, 0.f};
    f32x4 acc[2][4];
#pragma unroll
    for (int qg = 0; qg < 2; ++qg)
#pragma unroll
        for (int dg = 0; dg < 4; ++dg) acc[qg][dg] = (f32x4){0.f, 0.f, 0.f, 0.f};

    for (int pass = 0; pass < 2; ++pass) {
        if (pass) __syncthreads();              // all reads of old vT done
        {   // ---- stage V^T (f32 -> bf16, transpose scatter) ----
            const int key = t >> 1, d0 = (t & 1) * 32;
            const int krow = pass ? sidx[bh * SAMP + key] : ks[sbase + key];
            const float* vp = v + (((b * S + krow) * H + h) << 6) + d0;
#pragma unroll
            for (int i = 0; i < 4; ++i) {
                float4 y0 = ((const float4*)(vp + i * 8))[0];
                float4 y1 = ((const float4*)(vp + i * 8))[1];
                const int d = d0 + i * 8;
                vT[(d + 0) * VP + key] = f2bf(y0.x);
                vT[(d + 1) * VP + key] = f2bf(y0.y);
                vT[(d + 2) * VP + key] = f2bf(y0.z);
                vT[(d + 3) * VP + key] = f2bf(y0.w);
                vT[(d + 4) * VP + key] = f2bf(y1.x);
                vT[(d + 5) * VP + key] = f2bf(y1.y);
                vT[(d + 6) * VP + key] = f2bf(y1.z);
                vT[(d + 7) * VP + key] = f2bf(y1.w);
            }
        }
        __syncthreads();

        const float bias = pass ? LOG32 : 0.f;
        for (int kt4 = 0; kt4 < 4; ++kt4) {
            // ---- gathered key rows ----
            int krw[4];
#pragma unroll
            for (int kg = 0; kg < 4; ++kg) {
                const int key = kt4 * 64 + kg * 16 + lr;
                krw[kg] = pass ? sidx[bh * SAMP + key] : ks[sbase + key];
            }
            // ---- S^T = K Q^T  (A=K frags from f32, B=Q frags) ----
            f32x4 c[2][4];
#pragma unroll
            for (int kf = 0; kf < 2; ++kf) {
                float4 xr[4][2];
#pragma unroll
                for (int kg = 0; kg < 4; ++kg) {
                    const float* kr = k + (((b * S + krw[kg]) * H + h) << 6)
                                      + kf * 32 + lg * 8;
                    xr[kg][0] = ((const float4*)kr)[0];
                    xr[kg][1] = ((const float4*)kr)[1];
                }
                bf16x8 ak[4];
#pragma unroll
                for (int kg = 0; kg < 4; ++kg) {
                    union { bf16x8 v8; unsigned int u[4]; } fb;
                    fb.u[0] = pack2(xr[kg][0].x, xr[kg][0].y);
                    fb.u[1] = pack2(xr[kg][0].z, xr[kg][0].w);
                    fb.u[2] = pack2(xr[kg][1].x, xr[kg][1].y);
                    fb.u[3] = pack2(xr[kg][1].z, xr[kg][1].w);
                    ak[kg] = fb.v8;
                }
#pragma unroll
                for (int qg = 0; qg < 2; ++qg)
#pragma unroll
                    for (int kg = 0; kg < 4; ++kg) {
                        f32x4 cin = kf ? c[qg][kg] : (f32x4){0.f, 0.f, 0.f, 0.f};
                        c[qg][kg] = __builtin_amdgcn_mfma_f32_16x16x32_bf16(ak[kg], bq[qg][kf], cin, 0, 0, 0);
                    }
            }
            // ---- online softmax: keys mostly in-lane ----
            float esc[2];
#pragma unroll
            for (int qg = 0; qg < 2; ++qg) {
                float tm = -1e30f;
#pragma unroll
                for (int kg = 0; kg < 4; ++kg)
#pragma unroll
                    for (int r = 0; r < 4; ++r) tm = fmaxf(tm, c[qg][kg][r]);
                tm = fmaxf(tm, __shfl_xor(tm, 16));
                tm = fmaxf(tm, __shfl_xor(tm, 32));
                tm += bias;
                const float mn = fmaxf(m_run[qg], tm);
                esc[qg] = __expf(m_run[qg] - mn);
                m_run[qg] = mn;
                const float mnb = mn - bias;
                float rs = 0.f;
#pragma unroll
                for (int kg = 0; kg < 4; ++kg)
#pragma unroll
                    for (int r = 0; r < 4; ++r) {
                        const float p = __expf(c[qg][kg][r] - mnb);
                        c[qg][kg][r] = p;
                        rs += p;
                    }
                rs += __shfl_xor(rs, 16);
                rs += __shfl_xor(rs, 32);
                l_run[qg] = l_run[qg] * esc[qg] + rs;
            }
            // ---- rescale acc (esc lives per query=lr; acc rows = lg*4+r) ----
#pragma unroll
            for (int qg = 0; qg < 2; ++qg)
#pragma unroll
                for (int r = 0; r < 4; ++r) {
                    const float er = __shfl(esc[qg], lg * 4 + r);
#pragma unroll
                    for (int dg = 0; dg < 4; ++dg) acc[qg][dg][r] *= er;
                }
            // ---- PV in 32-key halves: packed P write, b128 reads ----
#pragma unroll
            for (int hh = 0; hh < 2; ++hh) {
#pragma unroll
                for (int qg = 0; qg < 2; ++qg)
#pragma unroll
                    for (int kg2 = 0; kg2 < 2; ++kg2) {
                        const int kg = hh * 2 + kg2;
                        uint2 u;
                        u.x = pack2(c[qg][kg][0], c[qg][kg][1]);
                        u.y = pack2(c[qg][kg][2], c[qg][kg][3]);
                        *(uint2*)&pw[(qg * 16 + lr) * PP + kg2 * 16 + lg * 4] = u;
                    }
                bf16x8 bv[4];
#pragma unroll
                for (int dg = 0; dg < 4; ++dg)
                    bv[dg] = *(const bf16x8*)&vT[(dg * 16 + lr) * VP + kt4 * 64 + hh * 32 + lg * 8];
#pragma unroll
                for (int qg = 0; qg < 2; ++qg) {
                    const bf16x8 ap = *(const bf16x8*)&pw[(qg * 16 + lr) * PP + lg * 8];
#pragma unroll
                    for (int dg = 0; dg < 4; ++dg)
                        acc[qg][dg] = __builtin_amdgcn_mfma_f32_16x16x32_bf16(ap, bv[dg], acc[qg][dg], 0, 0, 0);
                }
            }
        }
    }

    // ---- epilogue: out = acc / l, scattered to original query order ----
#pragma unroll
    for (int qg = 0; qg < 2; ++qg)
#pragma unroll
        for (int r = 0; r < 4; ++r) {
            const float lq = __shfl(l_run[qg], lg * 4 + r);
            const int   qr = __shfl(qrow[qg], lg * 4 + r);
            const float inv = 1.f / lq;
            const int obase = ((b * S + qr) * H + h) << 6;
#pragma unroll
            for (int dg = 0; dg < 4; ++dg)
                out[obase + dg * 16 + lr] = acc[qg][dg][r] * inv;
        }
}

// ---------------------------------------------------------------------------
extern "C" void kernel_launch(void* const* d_in, const int* in_sizes, int n_in,
                              void* d_out, int out_size, void* d_ws, size_t ws_size,
                              hipStream_t stream) {
    const float* q   = (const float*)d_in[0];
    const float* k   = (const float*)d_in[1];
    const float* v   = (const float*)d_in[2];
    const float* pd  = (const float*)d_in[3];
    const int*  sidx = (const int*)d_in[4];
    float* out = (float*)d_out;

    int* hq = (int*)d_ws;
    int* hk = hq + BHS;
    int* qs = hk + BHS;
    int* ks = qs + BHS;

    k_hash<<<B * (S / 16), 256, 0, stream>>>(q, k, pd, hq, hk);
    k_sort<<<2 * BH, SORT_NT, 0, stream>>>(hq, hk, qs, ks);
    k_attn<<<BH * NB, 512, 0, stream>>>(q, k, v, qs, ks, sidx, out);
}